// Round 3
// baseline (157.732 us; speedup 1.0000x reference)
//
#include <hip/hip_runtime.h>

typedef short bf16x8 __attribute__((ext_vector_type(8)));
typedef float f32x4 __attribute__((ext_vector_type(4)));

#define NTOK 262144
#define HH 100
#define DW 100
#define DT 25

__device__ __forceinline__ short f2bf(float f) {
    union { float f; unsigned u; } v; v.f = f;
    unsigned u = v.u + 0x7FFFu + ((v.u >> 16) & 1u);   // RNE bf16 (inputs finite)
    return (short)(u >> 16);
}

__device__ __forceinline__ float sigm(float x) {
    return __builtin_amdgcn_rcpf(1.f + __expf(-x));
}
__device__ __forceinline__ float tanh_(float x) {
    return 2.f * __builtin_amdgcn_rcpf(1.f + __expf(-2.f * x)) - 1.f;
}

// Each block: 4 waves x 64 tokens = 256 tokens.
// x fragments (K=125 padded to 128) held in registers across the whole gate loop.
// Per j-tile (16 of 100 h-columns), stage 24 bf16 B-fragments (6 gate groups x 4 K-steps)
// into LDS in MFMA-fragment-linear layout; every wave consumes all of them.
__global__ __launch_bounds__(256, 2)
void lstm_fused(const int* __restrict__ sent, const int* __restrict__ tags,
                const float* __restrict__ Ew, const float* __restrict__ Et,
                const float* __restrict__ Wf, const float* __restrict__ bif, const float* __restrict__ bhf,
                const float* __restrict__ Wb, const float* __restrict__ bib, const float* __restrict__ bhb,
                float* __restrict__ out)
{
    __shared__ bf16x8 wlds[24 * 64];   // 24 KiB
    const int tid  = threadIdx.x;
    const int lane = tid & 63;
    const int wave = tid >> 6;
    const int l15  = lane & 15;        // A row / B col within tile
    const int lg   = lane >> 4;        // k-group 0..3
    const int kb0  = lg * 8;
    const int tok_base = blockIdx.x * 256 + wave * 64;

    // ---- gather A fragments: x = [E_w row | E_t row | zero pad] as bf16 ----
    bf16x8 a[4][4];
    #pragma unroll
    for (int mt = 0; mt < 4; ++mt) {
        const int tok = tok_base + mt * 16 + l15;
        const float* ew = Ew + sent[tok] * DW;
        const float* et = Et + tags[tok] * DT;
        #pragma unroll
        for (int ks = 0; ks < 4; ++ks) {
            const int kb = ks * 32 + kb0;
            bf16x8 f;
            #pragma unroll
            for (int e = 0; e < 8; ++e) {
                const int k = kb + e;
                float v = 0.f;
                if (k < DW) v = ew[k];
                else if (k < DW + DT) v = et[k - DW];
                f[e] = f2bf(v);
            }
            a[mt][ks] = f;
        }
    }

    // gate row bases in W_ih (torch order i,f,g,o); forget gate unused (c0 == 0)
    const int gb0 = 0, gb1 = 2 * HH, gb2 = 3 * HH;

    for (int jt = 0; jt < 7; ++jt) {
        const int j  = jt * 16 + l15;
        const bool jv = (j < HH);
        __syncthreads();   // previous tile's LDS reads complete
        // ---- stage 24 B fragments (bf16, fragment-linear -> conflict-free b128) ----
        #pragma unroll
        for (int q = 0; q < 6; ++q) {
            const int fid = wave * 6 + q;          // 0..23
            const int g   = fid >> 2;              // 0..5 : (dir, gate)
            const int ks  = fid & 3;
            const float* W = (g < 3) ? Wf : Wb;
            const int gt  = (g < 3) ? g : g - 3;
            const int gbase = (gt == 0) ? gb0 : (gt == 1) ? gb1 : gb2;
            const float* wrow = W + (gbase + (jv ? j : 0)) * (DW + DT);
            const int kb = ks * 32 + kb0;
            bf16x8 f;
            #pragma unroll
            for (int e = 0; e < 8; ++e) {
                const int k = kb + e;
                float v = (jv && k < DW + DT) ? wrow[k] : 0.f;
                f[e] = f2bf(v);
            }
            wlds[fid * 64 + lane] = f;
        }
        __syncthreads();

        #pragma unroll
        for (int d = 0; d < 2; ++d) {
            bf16x8 b[3][4];
            #pragma unroll
            for (int gt = 0; gt < 3; ++gt)
                #pragma unroll
                for (int ks = 0; ks < 4; ++ks)
                    b[gt][ks] = wlds[((d * 3 + gt) * 4 + ks) * 64 + lane];

            const float* bi = d ? bib : bif;
            const float* bh = d ? bhb : bhf;
            float bias_i = 0.f, bias_g = 0.f, bias_o = 0.f;
            if (jv) {
                bias_i = bi[j]          + bh[j];
                bias_g = bi[2 * HH + j] + bh[2 * HH + j];
                bias_o = bi[3 * HH + j] + bh[3 * HH + j];
            }

            #pragma unroll
            for (int mt = 0; mt < 4; ++mt) {
                f32x4 acc0 = {0.f, 0.f, 0.f, 0.f};
                f32x4 acc1 = {0.f, 0.f, 0.f, 0.f};
                f32x4 acc2 = {0.f, 0.f, 0.f, 0.f};
                #pragma unroll
                for (int ks = 0; ks < 4; ++ks) {
                    acc0 = __builtin_amdgcn_mfma_f32_16x16x32_bf16(a[mt][ks], b[0][ks], acc0, 0, 0, 0);
                    acc1 = __builtin_amdgcn_mfma_f32_16x16x32_bf16(a[mt][ks], b[1][ks], acc1, 0, 0, 0);
                    acc2 = __builtin_amdgcn_mfma_f32_16x16x32_bf16(a[mt][ks], b[2][ks], acc2, 0, 0, 0);
                }
                if (jv) {
                    const int tokr = tok_base + mt * 16 + lg * 4;
                    #pragma unroll
                    for (int r = 0; r < 4; ++r) {
                        const float gi = acc0[r] + bias_i;
                        const float gg = acc1[r] + bias_g;
                        const float go = acc2[r] + bias_o;
                        const float c  = sigm(gi) * tanh_(gg);
                        const float h  = sigm(go) * tanh_(c);
                        out[(size_t)(tokr + r) * 200 + d * HH + j] = h;
                    }
                }
            }
        }
    }
}

extern "C" void kernel_launch(void* const* d_in, const int* in_sizes, int n_in,
                              void* d_out, int out_size, void* d_ws, size_t ws_size,
                              hipStream_t stream) {
    (void)in_sizes; (void)n_in; (void)out_size; (void)d_ws; (void)ws_size;
    lstm_fused<<<dim3(NTOK / 256), dim3(256), 0, stream>>>(
        (const int*)d_in[0], (const int*)d_in[1],
        (const float*)d_in[2], (const float*)d_in[3],
        (const float*)d_in[4], (const float*)d_in[5], (const float*)d_in[6],
        (const float*)d_in[7], (const float*)d_in[8], (const float*)d_in[9],
        (float*)d_out);
}

// Round 4
// 116.994 us; speedup vs baseline: 1.3482x; 1.3482x over previous
//
#include <hip/hip_runtime.h>

typedef short bf16x8 __attribute__((ext_vector_type(8)));
typedef float f32x4 __attribute__((ext_vector_type(4)));

#define NTOK 262144
#define HH 100
#define DW 100
#define DT 25
#define KK 125

__device__ __forceinline__ short f2bf(float f) {
    union { float f; unsigned u; } v; v.f = f;
    unsigned u = v.u + 0x7FFFu + ((v.u >> 16) & 1u);   // RNE bf16 (inputs finite)
    return (short)(u >> 16);
}

__device__ __forceinline__ float sigm(float x) {
    return __builtin_amdgcn_rcpf(1.f + __expf(-x));
}
__device__ __forceinline__ float tanh_(float x) {
    return 2.f * __builtin_amdgcn_rcpf(1.f + __expf(-2.f * x)) - 1.f;
}

// ---------------- pre-kernel: build B fragments + folded biases in ws ----------------
// bfrag layout: [jt(7)][d(2)][gt(3)][ks(4)][lane(64)] bf16x8  (= 172032 B)
// bias3 layout: [jt(7)][d(2)][gt(3)][l15(16)] float           (= 2688 B)
__global__ __launch_bounds__(256)
void build_b(const float* __restrict__ Wf, const float* __restrict__ bif, const float* __restrict__ bhf,
             const float* __restrict__ Wb, const float* __restrict__ bib, const float* __restrict__ bhb,
             bf16x8* __restrict__ bfrag, float* __restrict__ bias3)
{
    const int gwid = (blockIdx.x * 256 + threadIdx.x) >> 6;
    const int lane = threadIdx.x & 63;
    if (gwid >= 168) return;
    const int jt = gwid / 24, rem = gwid % 24;
    const int d  = rem / 12, gt = (rem % 12) / 4, ks = rem % 4;
    const int l15 = lane & 15, lg = lane >> 4;
    const int j = jt * 16 + l15;
    const bool jv = (j < HH);
    const float* W = d ? Wb : Wf;
    const int gbase = (gt == 0) ? 0 : (gt == 1) ? 2 * HH : 3 * HH;   // i, g, o (f dead: c0==0)
    const float* wrow = W + (size_t)(gbase + (jv ? j : 0)) * KK;
    bf16x8 f;
    #pragma unroll
    for (int e = 0; e < 8; ++e) {
        const int k = ks * 32 + lg * 8 + e;
        const float v = (jv && k < KK) ? wrow[k] : 0.f;
        f[e] = f2bf(v);
    }
    bfrag[((jt * 2 + d) * 12 + gt * 4 + ks) * 64 + lane] = f;
    if (ks == 0 && lg == 0) {
        const float* bi = d ? bib : bif;
        const float* bh = d ? bhb : bhf;
        const float bv = jv ? (bi[gbase + j] + bh[gbase + j]) : 0.f;
        bias3[((jt * 2 + d) * 3 + gt) * 16 + l15] = bv;
    }
}

// ---------------- main kernel: no LDS, no barriers ----------------
// 4 waves x 64 tokens per block; A fragments in registers for the whole kernel.
__global__ __launch_bounds__(256, 3)
void lstm_main(const int* __restrict__ sent, const int* __restrict__ tags,
               const float* __restrict__ Ew, const float* __restrict__ Et,
               const bf16x8* __restrict__ bfrag, const float* __restrict__ bias3,
               float* __restrict__ out)
{
    const int tid  = threadIdx.x;
    const int lane = tid & 63;
    const int wave = tid >> 6;
    const int l15  = lane & 15;
    const int lg   = lane >> 4;
    const int kb0  = lg * 8;
    const int tok_base = blockIdx.x * 256 + wave * 64;

    // ---- gather A fragments (vectorized): x = [E_w row | E_t row | pad] ----
    bf16x8 a[4][4];
    #pragma unroll
    for (int mt = 0; mt < 4; ++mt) {
        const int tok = tok_base + mt * 16 + l15;
        const float* ew = Ew + (size_t)sent[tok] * DW;
        const float* et = Et + (size_t)tags[tok] * DT;
        #pragma unroll
        for (int ks = 0; ks < 3; ++ks) {          // k in [0,96): pure E_w, 16B-aligned
            const float* p = ew + ks * 32 + kb0;
            const float4 v0 = *(const float4*)p;
            const float4 v1 = *(const float4*)(p + 4);
            bf16x8 f;
            f[0] = f2bf(v0.x); f[1] = f2bf(v0.y); f[2] = f2bf(v0.z); f[3] = f2bf(v0.w);
            f[4] = f2bf(v1.x); f[5] = f2bf(v1.y); f[6] = f2bf(v1.z); f[7] = f2bf(v1.w);
            a[mt][ks] = f;
        }
        {   // ks == 3: k in [96,128) -> E_w tail / E_t / zero pad
            float v[8];
            if (lg == 0) {
                const float4 w = *(const float4*)(ew + 96);
                v[0] = w.x; v[1] = w.y; v[2] = w.z; v[3] = w.w;
                #pragma unroll
                for (int e = 0; e < 4; ++e) v[4 + e] = et[e];
            } else {
                const int base = lg * 8 - 4;       // E_t index of elem 0
                #pragma unroll
                for (int e = 0; e < 8; ++e) {
                    const int ti = base + e;
                    v[e] = (ti < DT) ? et[ti] : 0.f;
                }
            }
            bf16x8 f;
            #pragma unroll
            for (int e = 0; e < 8; ++e) f[e] = f2bf(v[e]);
            a[mt][3] = f;
        }
    }

    for (int jt = 0; jt < 7; ++jt) {
        const int j  = jt * 16 + l15;
        const bool jv = (j < HH);
        #pragma unroll
        for (int d = 0; d < 2; ++d) {
            const int td = (jt * 2 + d);
            // 12 coalesced dwordx4 loads (L2-resident, shared by every block)
            bf16x8 b[3][4];
            #pragma unroll
            for (int gt = 0; gt < 3; ++gt)
                #pragma unroll
                for (int ks = 0; ks < 4; ++ks)
                    b[gt][ks] = bfrag[(td * 12 + gt * 4 + ks) * 64 + lane];
            const float bias_i = bias3[(td * 3 + 0) * 16 + l15];
            const float bias_g = bias3[(td * 3 + 1) * 16 + l15];
            const float bias_o = bias3[(td * 3 + 2) * 16 + l15];

            #pragma unroll
            for (int mt = 0; mt < 4; ++mt) {
                f32x4 acc0 = {0.f, 0.f, 0.f, 0.f};
                f32x4 acc1 = {0.f, 0.f, 0.f, 0.f};
                f32x4 acc2 = {0.f, 0.f, 0.f, 0.f};
                #pragma unroll
                for (int ks = 0; ks < 4; ++ks) {
                    acc0 = __builtin_amdgcn_mfma_f32_16x16x32_bf16(a[mt][ks], b[0][ks], acc0, 0, 0, 0);
                    acc1 = __builtin_amdgcn_mfma_f32_16x16x32_bf16(a[mt][ks], b[1][ks], acc1, 0, 0, 0);
                    acc2 = __builtin_amdgcn_mfma_f32_16x16x32_bf16(a[mt][ks], b[2][ks], acc2, 0, 0, 0);
                }
                if (jv) {
                    const int tokr = tok_base + mt * 16 + lg * 4;
                    #pragma unroll
                    for (int r = 0; r < 4; ++r) {
                        const float gi = acc0[r] + bias_i;
                        const float gg = acc1[r] + bias_g;
                        const float go = acc2[r] + bias_o;
                        const float c  = sigm(gi) * tanh_(gg);
                        const float h  = sigm(go) * tanh_(c);
                        out[(size_t)(tokr + r) * 200 + d * HH + j] = h;
                    }
                }
            }
        }
    }
}

extern "C" void kernel_launch(void* const* d_in, const int* in_sizes, int n_in,
                              void* d_out, int out_size, void* d_ws, size_t ws_size,
                              hipStream_t stream) {
    (void)in_sizes; (void)n_in; (void)out_size; (void)ws_size;
    bf16x8* bfrag = (bf16x8*)d_ws;                       // 172032 B
    float*  bias3 = (float*)((char*)d_ws + 172032);      // 2688 B
    build_b<<<dim3(42), dim3(256), 0, stream>>>(
        (const float*)d_in[4], (const float*)d_in[5], (const float*)d_in[6],
        (const float*)d_in[7], (const float*)d_in[8], (const float*)d_in[9],
        bfrag, bias3);
    lstm_main<<<dim3(NTOK / 256), dim3(256), 0, stream>>>(
        (const int*)d_in[0], (const int*)d_in[1],
        (const float*)d_in[2], (const float*)d_in[3],
        bfrag, bias3, (float*)d_out);
}

// Round 5
// 109.736 us; speedup vs baseline: 1.4374x; 1.0661x over previous
//
#include <hip/hip_runtime.h>

typedef short bf16x8 __attribute__((ext_vector_type(8)));
typedef float f32x4 __attribute__((ext_vector_type(4)));

#define NTOK 262144
#define HH 100
#define DW 100
#define DT 25
#define KK 125

__device__ __forceinline__ short f2bf(float f) {
    union { float f; unsigned u; } v; v.f = f;
    unsigned u = v.u + 0x7FFFu + ((v.u >> 16) & 1u);   // RNE bf16 (inputs finite)
    return (short)(u >> 16);
}

__device__ __forceinline__ float sigm(float x) {
    return __builtin_amdgcn_rcpf(1.f + __expf(-x));
}
__device__ __forceinline__ float tanh_(float x) {
    return 2.f * __builtin_amdgcn_rcpf(1.f + __expf(-2.f * x)) - 1.f;
}

// ---------------- pre-kernel: build B fragments + folded biases in ws ----------------
// bfrag layout: [jt(7)][d(2)][gt(3)][ks(4)][lane(64)] bf16x8  (= 172032 B)
// bias3 layout: [d(2)][gt(3)][jpad(112)] float                (= 2688 B)
__global__ __launch_bounds__(256)
void build_b(const float* __restrict__ Wf, const float* __restrict__ bif, const float* __restrict__ bhf,
             const float* __restrict__ Wb, const float* __restrict__ bib, const float* __restrict__ bhb,
             bf16x8* __restrict__ bfrag, float* __restrict__ bias3)
{
    const int gwid = (blockIdx.x * 256 + threadIdx.x) >> 6;
    const int lane = threadIdx.x & 63;
    if (gwid >= 168) return;
    const int jt = gwid / 24, rem = gwid % 24;
    const int d  = rem / 12, gt = (rem % 12) / 4, ks = rem % 4;
    const int l15 = lane & 15, lg = lane >> 4;
    const int j = jt * 16 + l15;
    const bool jv = (j < HH);
    const float* W = d ? Wb : Wf;
    const int gbase = (gt == 0) ? 0 : (gt == 1) ? 2 * HH : 3 * HH;   // i, g, o (f dead: c0==0)
    const float* wrow = W + (size_t)(gbase + (jv ? j : 0)) * KK;
    bf16x8 f;
    #pragma unroll
    for (int e = 0; e < 8; ++e) {
        const int k = ks * 32 + lg * 8 + e;
        const float v = (jv && k < KK) ? wrow[k] : 0.f;
        f[e] = f2bf(v);
    }
    bfrag[((jt * 2 + d) * 12 + gt * 4 + ks) * 64 + lane] = f;
    if (ks == 0 && lg == 0) {
        const float* bi = d ? bib : bif;
        const float* bh = d ? bhb : bhf;
        bias3[(d * 3 + gt) * 112 + jt * 16 + l15] =
            jv ? (bi[gbase + j] + bh[gbase + j]) : 0.f;
    }
}

// ---------------- main kernel ----------------
// 4 waves x 32 tokens per block (128 tokens), grid 2048 -> 8192 waves total.
// Operand-swapped MFMA: D[row=j][col=token]; each lane holds 4 consecutive j of
// one token -> f32x4 stores. W slab for the current jt staged in LDS (24 KB).
__global__ __launch_bounds__(256, 5)
void lstm_main(const int* __restrict__ sent, const int* __restrict__ tags,
               const float* __restrict__ Ew, const float* __restrict__ Et,
               const bf16x8* __restrict__ bfrag, const float* __restrict__ bias3,
               float* __restrict__ out)
{
    __shared__ bf16x8 wlds[24 * 64];   // 24 KiB: [d(2)][gt(3)][ks(4)][lane(64)]
    const int tid  = threadIdx.x;
    const int lane = tid & 63;
    const int wave = tid >> 6;
    const int l15  = lane & 15;        // token within 16-tile
    const int lg   = lane >> 4;        // k-group (inputs) / j-quad (output)
    const int kb0  = lg * 8;
    const int tok_base = blockIdx.x * 128 + wave * 32;

    // ---- gather x fragments (MFMA B-operand): x = [E_w row | E_t row | pad] ----
    bf16x8 a[2][4];
    #pragma unroll
    for (int mt = 0; mt < 2; ++mt) {
        const int tok = tok_base + mt * 16 + l15;
        const float* ew = Ew + (size_t)sent[tok] * DW;
        const float* et = Et + (size_t)tags[tok] * DT;
        #pragma unroll
        for (int ks = 0; ks < 3; ++ks) {          // k in [0,96): pure E_w, 16B-aligned
            const float* p = ew + ks * 32 + kb0;
            const float4 v0 = *(const float4*)p;
            const float4 v1 = *(const float4*)(p + 4);
            bf16x8 f;
            f[0] = f2bf(v0.x); f[1] = f2bf(v0.y); f[2] = f2bf(v0.z); f[3] = f2bf(v0.w);
            f[4] = f2bf(v1.x); f[5] = f2bf(v1.y); f[6] = f2bf(v1.z); f[7] = f2bf(v1.w);
            a[mt][ks] = f;
        }
        {   // ks == 3: k in [96,128) -> E_w tail / E_t / zero pad
            float v[8];
            if (lg == 0) {
                const float4 w = *(const float4*)(ew + 96);
                v[0] = w.x; v[1] = w.y; v[2] = w.z; v[3] = w.w;
                #pragma unroll
                for (int e = 0; e < 4; ++e) v[4 + e] = et[e];
            } else {
                const int base = lg * 8 - 4;       // E_t index of elem 0
                #pragma unroll
                for (int e = 0; e < 8; ++e) {
                    const int ti = base + e;
                    v[e] = (ti < DT) ? et[ti] : 0.f;
                }
            }
            bf16x8 f;
            #pragma unroll
            for (int e = 0; e < 8; ++e) f[e] = f2bf(v[e]);
            a[mt][3] = f;
        }
    }

    for (int jt = 0; jt < 7; ++jt) {
        // issue stage loads early (latency overlaps previous tile's epilogue)
        bf16x8 st[6];
        #pragma unroll
        for (int q = 0; q < 6; ++q)
            st[q] = bfrag[(size_t)(jt * 24 + wave * 6 + q) * 64 + lane];
        __syncthreads();                   // previous tile's LDS reads complete
        #pragma unroll
        for (int q = 0; q < 6; ++q)
            wlds[(wave * 6 + q) * 64 + lane] = st[q];
        __syncthreads();

        const bool sv = (jt < 6) || (lg == 0);   // j-quad valid (j<100)

        #pragma unroll
        for (int d = 0; d < 2; ++d) {
            f32x4 acc[2][3];
            #pragma unroll
            for (int gt = 0; gt < 3; ++gt) {
                // bias pre-folded into accumulator init (row = j = jt*16+lg*4+r)
                const f32x4 bv = *(const f32x4*)&bias3[(size_t)(d * 3 + gt) * 112 + jt * 16 + lg * 4];
                acc[0][gt] = bv;
                acc[1][gt] = bv;
                bf16x8 b[4];
                #pragma unroll
                for (int ks = 0; ks < 4; ++ks)
                    b[ks] = wlds[(d * 12 + gt * 4 + ks) * 64 + lane];
                #pragma unroll
                for (int mt = 0; mt < 2; ++mt)
                    #pragma unroll
                    for (int ks = 0; ks < 4; ++ks)
                        acc[mt][gt] = __builtin_amdgcn_mfma_f32_16x16x32_bf16(
                            b[ks], a[mt][ks], acc[mt][gt], 0, 0, 0);
            }
            if (sv) {
                #pragma unroll
                for (int mt = 0; mt < 2; ++mt) {
                    const int tok = tok_base + mt * 16 + l15;
                    f32x4 h;
                    #pragma unroll
                    for (int r = 0; r < 4; ++r) {
                        const float c = sigm(acc[mt][0][r]) * tanh_(acc[mt][1][r]);
                        h[r] = sigm(acc[mt][2][r]) * tanh_(c);
                    }
                    *(f32x4*)&out[(size_t)tok * 200 + d * HH + jt * 16 + lg * 4] = h;
                }
            }
        }
    }
}

extern "C" void kernel_launch(void* const* d_in, const int* in_sizes, int n_in,
                              void* d_out, int out_size, void* d_ws, size_t ws_size,
                              hipStream_t stream) {
    (void)in_sizes; (void)n_in; (void)out_size; (void)ws_size;
    bf16x8* bfrag = (bf16x8*)d_ws;                       // 172032 B
    float*  bias3 = (float*)((char*)d_ws + 172032);      // 2688 B
    build_b<<<dim3(42), dim3(256), 0, stream>>>(
        (const float*)d_in[4], (const float*)d_in[5], (const float*)d_in[6],
        (const float*)d_in[7], (const float*)d_in[8], (const float*)d_in[9],
        bfrag, bias3);
    lstm_main<<<dim3(NTOK / 128), dim3(256), 0, stream>>>(
        (const int*)d_in[0], (const int*)d_in[1],
        (const float*)d_in[2], (const float*)d_in[3],
        bfrag, bias3, (float*)d_out);
}

// Round 6
// 105.812 us; speedup vs baseline: 1.4907x; 1.0371x over previous
//
#include <hip/hip_runtime.h>

typedef short bf16x8 __attribute__((ext_vector_type(8)));
typedef float f32x4 __attribute__((ext_vector_type(4)));

#define NTOK 262144
#define HH 100
#define DW 100
#define DT 25
#define KK 125

__device__ __forceinline__ short f2bf(float f) {
    union { float f; unsigned u; } v; v.f = f;
    unsigned u = v.u + 0x7FFFu + ((v.u >> 16) & 1u);   // RNE bf16 (inputs finite)
    return (short)(u >> 16);
}

__device__ __forceinline__ float sigm(float x) {
    return __builtin_amdgcn_rcpf(1.f + __expf(-x));
}
__device__ __forceinline__ float tanh_(float x) {
    return 2.f * __builtin_amdgcn_rcpf(1.f + __expf(-2.f * x)) - 1.f;
}

// ---------------- pre-kernel: build B fragments + folded biases in ws ----------------
// bfrag layout: [d(2)][jt(7)][fid(12 = gt*4+ks)][lane(64)] bf16x8  (= 172032 B)
// bias3 layout: [d(2)][gt(3)][jpad(112)] float                     (= 2688 B)
__global__ __launch_bounds__(256)
void build_b(const float* __restrict__ Wf, const float* __restrict__ bif, const float* __restrict__ bhf,
             const float* __restrict__ Wb, const float* __restrict__ bib, const float* __restrict__ bhb,
             bf16x8* __restrict__ bfrag, float* __restrict__ bias3)
{
    const int gwid = (blockIdx.x * 256 + threadIdx.x) >> 6;   // 0..167
    const int lane = threadIdx.x & 63;
    if (gwid >= 168) return;
    const int d   = gwid / 84;
    const int rem = gwid % 84;           // jt*12 + fid
    const int jt  = rem / 12, fid = rem % 12;
    const int gt  = fid >> 2, ks = fid & 3;
    const int l15 = lane & 15, lg = lane >> 4;
    const int j = jt * 16 + l15;
    const bool jv = (j < HH);
    const float* W = d ? Wb : Wf;
    const int gbase = (gt == 0) ? 0 : (gt == 1) ? 2 * HH : 3 * HH;   // i, g, o (f dead: c0==0)
    const float* wrow = W + (size_t)(gbase + (jv ? j : 0)) * KK;
    bf16x8 f;
    #pragma unroll
    for (int e = 0; e < 8; ++e) {
        const int k = ks * 32 + lg * 8 + e;
        const float v = (jv && k < KK) ? wrow[k] : 0.f;
        f[e] = f2bf(v);
    }
    bfrag[(size_t)gwid * 64 + lane] = f;
    if (ks == 0 && lg == 0) {
        const float* bi = d ? bib : bif;
        const float* bh = d ? bhb : bhf;
        bias3[(d * 3 + gt) * 112 + jt * 16 + l15] =
            jv ? (bi[gbase + j] + bh[gbase + j]) : 0.f;
    }
}

// ---------------- main kernel: zero barriers, per-wave private h-staging ----------------
// 4 waves x 32 tokens per block (128 tokens), grid 2048.
// Operand-swapped MFMA: D[row=j][col=token]; bias folded into acc init.
// Per direction d: compute all 7 j-tiles into LDS staging (packed 100 f32/token),
// then flush as dense contiguous 1KB wave-stores (kills the 64B-island straddle
// amplification seen in rounds 3-5: WRITE_SIZE 301MB vs 210MB ideal).
__global__ __launch_bounds__(256, 3)
void lstm_main(const int* __restrict__ sent, const int* __restrict__ tags,
               const float* __restrict__ Ew, const float* __restrict__ Et,
               const bf16x8* __restrict__ bfrag, const float* __restrict__ bias3,
               float* __restrict__ out)
{
    __shared__ float hstage[4][32 * 100];   // 51200 B, per-wave private regions
    const int tid  = threadIdx.x;
    const int lane = tid & 63;
    const int wave = tid >> 6;
    const int l15  = lane & 15;        // token within 16-tile
    const int lg   = lane >> 4;        // k-group (inputs) / j-quad (output)
    const int kb0  = lg * 8;
    const int tok_base = blockIdx.x * 128 + wave * 32;

    // ---- gather x fragments (MFMA B-operand): x = [E_w row | E_t row | pad] ----
    bf16x8 a[2][4];
    #pragma unroll
    for (int mt = 0; mt < 2; ++mt) {
        const int tok = tok_base + mt * 16 + l15;
        const float* ew = Ew + (size_t)sent[tok] * DW;
        const float* et = Et + (size_t)tags[tok] * DT;
        #pragma unroll
        for (int ks = 0; ks < 3; ++ks) {          // k in [0,96): pure E_w, 16B-aligned
            const float* p = ew + ks * 32 + kb0;
            const float4 v0 = *(const float4*)p;
            const float4 v1 = *(const float4*)(p + 4);
            bf16x8 f;
            f[0] = f2bf(v0.x); f[1] = f2bf(v0.y); f[2] = f2bf(v0.z); f[3] = f2bf(v0.w);
            f[4] = f2bf(v1.x); f[5] = f2bf(v1.y); f[6] = f2bf(v1.z); f[7] = f2bf(v1.w);
            a[mt][ks] = f;
        }
        {   // ks == 3: k in [96,128) -> E_w tail / E_t / zero pad
            float v[8];
            if (lg == 0) {
                const float4 w = *(const float4*)(ew + 96);
                v[0] = w.x; v[1] = w.y; v[2] = w.z; v[3] = w.w;
                #pragma unroll
                for (int e = 0; e < 4; ++e) v[4 + e] = et[e];
            } else {
                const int base = lg * 8 - 4;       // E_t index of elem 0
                #pragma unroll
                for (int e = 0; e < 8; ++e) {
                    const int ti = base + e;
                    v[e] = (ti < DT) ? et[ti] : 0.f;
                }
            }
            bf16x8 f;
            #pragma unroll
            for (int e = 0; e < 8; ++e) f[e] = f2bf(v[e]);
            a[mt][3] = f;
        }
    }

    float* hs = hstage[wave];

    for (int d = 0; d < 2; ++d) {
        #pragma unroll
        for (int jt = 0; jt < 7; ++jt) {
            // 12 W fragments straight from L2-resident bfrag (lane-indexed b128 loads)
            const bf16x8* bp = bfrag + ((size_t)(d * 7 + jt) * 12) * 64 + lane;
            bf16x8 b[12];
            #pragma unroll
            for (int f = 0; f < 12; ++f) b[f] = bp[(size_t)f * 64];

            f32x4 acc[2][3];
            #pragma unroll
            for (int gt = 0; gt < 3; ++gt) {
                // bias pre-folded into accumulator init (row = j = jt*16+lg*4+r)
                const f32x4 bv = *(const f32x4*)&bias3[(size_t)(d * 3 + gt) * 112 + jt * 16 + lg * 4];
                acc[0][gt] = bv;
                acc[1][gt] = bv;
                #pragma unroll
                for (int mt = 0; mt < 2; ++mt)
                    #pragma unroll
                    for (int ks = 0; ks < 4; ++ks)
                        acc[mt][gt] = __builtin_amdgcn_mfma_f32_16x16x32_bf16(
                            b[gt * 4 + ks], a[mt][ks], acc[mt][gt], 0, 0, 0);
            }

            const bool sv = (jt < 6) || (lg == 0);   // j-quad valid (j<100)
            if (sv) {
                #pragma unroll
                for (int mt = 0; mt < 2; ++mt) {
                    f32x4 h;
                    #pragma unroll
                    for (int r = 0; r < 4; ++r) {
                        const float c = sigm(acc[mt][0][r]) * tanh_(acc[mt][1][r]);
                        h[r] = sigm(acc[mt][2][r]) * tanh_(c);
                    }
                    // packed staging: [token(32)][j(100)] f32; bank-window (l15+lg)%8 uniform
                    *(f32x4*)&hs[(mt * 16 + l15) * 100 + jt * 16 + lg * 4] = h;
                }
            }
        }
        // ---- dense flush: 32 tokens x 400B islands, 1KB fully-dense per wave-store ----
        float* dst = out + (size_t)tok_base * 200 + d * 100;
        #pragma unroll
        for (int it = 0; it < 13; ++it) {
            const int fd = it * 256 + lane * 4;     // dword offset in packed space
            if (fd < 3200) {
                const int t = fd / 100;             // token (magic-mul)
                const f32x4 v = *(const f32x4*)&hs[fd];
                *(f32x4*)&dst[fd + t * 100] = v;    // = dst[t*200 + (fd - t*100)]
            }
        }
    }
}

extern "C" void kernel_launch(void* const* d_in, const int* in_sizes, int n_in,
                              void* d_out, int out_size, void* d_ws, size_t ws_size,
                              hipStream_t stream) {
    (void)in_sizes; (void)n_in; (void)out_size; (void)ws_size;
    bf16x8* bfrag = (bf16x8*)d_ws;                       // 172032 B
    float*  bias3 = (float*)((char*)d_ws + 172032);      // 2688 B
    build_b<<<dim3(42), dim3(256), 0, stream>>>(
        (const float*)d_in[4], (const float*)d_in[5], (const float*)d_in[6],
        (const float*)d_in[7], (const float*)d_in[8], (const float*)d_in[9],
        bfrag, bias3);
    lstm_main<<<dim3(NTOK / 128), dim3(256), 0, stream>>>(
        (const int*)d_in[0], (const int*)d_in[1],
        (const float*)d_in[2], (const float*)d_in[3],
        bfrag, bias3, (float*)d_out);
}